// Round 4
// baseline (127.611 us; speedup 1.0000x reference)
//
#include <hip/hip_runtime.h>
#include <stdint.h>

// ---- problem constants ----
#define NPARTS 16
#define NK1    257            // rows per part (hash values 0..256)
#define ROWS   4112           // 257*16 distinct embedding rows
#define MPAD   4224           // 66*64, padded GEMM M
#define VAE    768
#define ODIM   1024
#define BROWS  65536          // 4096*16 output rows
#define BPART  4096           // output rows per part

typedef __attribute__((ext_vector_type(4))) float f32x4;
typedef __attribute__((ext_vector_type(8))) short s16x8;

static __device__ __forceinline__ unsigned short f2bf(float f) {
  union { float f; unsigned u; } v; v.f = f;
  unsigned x = v.u;
  unsigned r = x + 0x7FFFu + ((x >> 16) & 1u);   // RNE
  return (unsigned short)(r >> 16);
}

static __device__ __forceinline__ void gload_lds16(const void* g, void* l) {
  __builtin_amdgcn_global_load_lds(
      (const __attribute__((address_space(1))) unsigned int*)g,
      (__attribute__((address_space(3))) unsigned int*)l, 16, 0, 0);
}

// ---------------- prep: emb->bf16 cast | W1 transpose-cast | inverse-index build ----
// grid: [0,1024) emb cast; [1024,1792) W1 32x32 tiles; [1792,1808) idx build (16 parts)
#define EMB_BLOCKS 1024
#define W1_BLOCKS  768
__global__ __launch_bounds__(256) void prep_kernel(
    const float* __restrict__ emb, const float* __restrict__ W1,
    const int* __restrict__ hashes,
    unsigned short* __restrict__ embB, unsigned short* __restrict__ w1t,
    int* __restrict__ gcnt, int* __restrict__ gbase, int* __restrict__ rowlist) {
  __shared__ unsigned short tile[32][33];
  __shared__ int hist[512];
  const int tid = threadIdx.x;
  const int bid = blockIdx.x;
  if (bid < EMB_BLOCKS) {
    const int NQ = MPAD * VAE / 4;   // 811008 quads
    for (int g = bid * 256 + tid; g < NQ; g += EMB_BLOCKS * 256) {
      const int i4 = g * 4;
      ushort4 o;
      if (i4 < ROWS * VAE) {
        const float4 v = *(const float4*)(emb + i4);
        o.x = f2bf(v.x); o.y = f2bf(v.y); o.z = f2bf(v.z); o.w = f2bf(v.w);
      } else {
        o.x = 0; o.y = 0; o.z = 0; o.w = 0;
      }
      *(ushort4*)(embB + i4) = o;
    }
  } else if (bid < EMB_BLOCKS + W1_BLOCKS) {
    const int tb = bid - EMB_BLOCKS;         // 24 k-tiles x 32 n-tiles
    const int nkt = VAE / 32;
    const int tk = (tb % nkt) * 32;
    const int tn = (tb / nkt) * 32;
    const int r  = tid >> 3;
    const int c4 = (tid & 7) * 4;
    const float4 v = *(const float4*)(W1 + (size_t)(tk + r) * ODIM + tn + c4);
    tile[r][c4 + 0] = f2bf(v.x);
    tile[r][c4 + 1] = f2bf(v.y);
    tile[r][c4 + 2] = f2bf(v.z);
    tile[r][c4 + 3] = f2bf(v.w);
    __syncthreads();
    ushort4 o;
    o.x = tile[c4 + 0][r];
    o.y = tile[c4 + 1][r];
    o.z = tile[c4 + 2][r];
    o.w = tile[c4 + 3][r];
    *(ushort4*)(w1t + (size_t)(tn + r) * VAE + tk + c4) = o;
  } else {
    // ---- inverse index for part p: counting sort of 4096 rows into 257 buckets ----
    const int p = bid - (EMB_BLOCKS + W1_BLOCKS);
    hist[tid] = 0; hist[tid + 256] = 0;
    __syncthreads();
    int hv[16];
#pragma unroll
    for (int u = 0; u < 16; ++u) {
      const int b = u * 256 + tid;
      hv[u] = hashes[b * NPARTS + p];
      atomicAdd(&hist[hv[u]], 1);
    }
    __syncthreads();
    const int o0 = hist[tid], o1 = hist[tid + 256];
    // inclusive Hillis-Steele scan over 512 (2 slots/thread)
    for (int off = 1; off < 512; off <<= 1) {
      const int v0 = (tid >= off) ? hist[tid - off] : 0;
      const int v1 = hist[tid + 256 - off];
      __syncthreads();
      hist[tid] += v0; hist[tid + 256] += v1;
      __syncthreads();
    }
    const int b0 = hist[tid] - o0;          // exclusive base
    const int b1 = hist[tid + 256] - o1;
    gcnt[p * NK1 + tid]  = o0;
    gbase[p * NK1 + tid] = b0;
    if (tid == 0) { gcnt[p * NK1 + 256] = o1; gbase[p * NK1 + 256] = b1; }
    if (p == 0 && tid < MPAD - ROWS) { gcnt[ROWS + tid] = 0; gbase[ROWS + tid] = 0; }
    __syncthreads();
    hist[tid] = b0; hist[tid + 256] = b1;   // cursors
    __syncthreads();
#pragma unroll
    for (int u = 0; u < 16; ++u) {
      const int b = u * 256 + tid;
      const int pos = atomicAdd(&hist[hv[u]], 1);
      rowlist[p * BPART + pos] = b * NPARTS + p;
    }
  }
}

// ---------------- 64x128-tile bf16 MFMA GEMM ----------------
// 2-phase dbuf, BK=64, XOR-swizzled staging (swizzled global src + linear LDS
// dest [m104/m108], swizzled ds_read [rule #21]).
// MODE 0: out = relu(acc+bias) -> bf16 H     (+ z==1 blocks transpose-cast W2)
// MODE 2: scatter epilogue: v = acc+bias+pe[trow/257]; for each consumer row in
//         CSR(rowlist), nontemporal-store the 128-col slice of out.
template <int K, int MODE, bool DO_W2T>
__global__ __launch_bounds__(256) void gemm_kernel(
    const unsigned short* __restrict__ A, const unsigned short* __restrict__ BT,
    const float* __restrict__ bias, const float* __restrict__ pe,
    unsigned short* __restrict__ outB, float* __restrict__ outF,
    const float* __restrict__ W2src, unsigned short* __restrict__ w2dst,
    const int* __restrict__ gcnt, const int* __restrict__ gbase,
    const int* __restrict__ rowlist) {
  __shared__ __align__(16) unsigned short smem[2 * 12288];   // 48 KB staging
  const int tid = threadIdx.x;

  if (DO_W2T && blockIdx.z == 1) {
    if (blockIdx.y >= 32) return;
    unsigned short (*ttile)[132] = (unsigned short (*)[132])smem;
    const int tk = blockIdx.y * 32, tn = blockIdx.x * 128;
#pragma unroll
    for (int q = 0; q < 4; ++q) {
      const int row = (tid >> 5) + q * 8, c4 = (tid & 31) * 4;
      const float4 v = *(const float4*)(W2src + (size_t)(tk + row) * ODIM + tn + c4);
      ttile[row][c4 + 0] = f2bf(v.x); ttile[row][c4 + 1] = f2bf(v.y);
      ttile[row][c4 + 2] = f2bf(v.z); ttile[row][c4 + 3] = f2bf(v.w);
    }
    __syncthreads();
#pragma unroll
    for (int q = 0; q < 4; ++q) {
      const int n = (tid >> 3) + q * 32, k4 = (tid & 7) * 4;
      ushort4 o;
      o.x = ttile[k4 + 0][n]; o.y = ttile[k4 + 1][n];
      o.z = ttile[k4 + 2][n]; o.w = ttile[k4 + 3][n];
      *(ushort4*)(w2dst + (size_t)(tn + n) * ODIM + tk + k4) = o;
    }
    return;
  }

  const int lane = tid & 63;
  const int wave = tid >> 6;
  const int wc   = wave * 32;
  const int brow = blockIdx.y * 64;
  const int bcol = blockIdx.x * 128;
  const int la   = lane & 15;
  const int hi   = lane >> 4;

  f32x4 acc[4][2];
#pragma unroll
  for (int m = 0; m < 4; ++m)
#pragma unroll
    for (int n = 0; n < 2; ++n)
#pragma unroll
      for (int r = 0; r < 4; ++r) acc[m][n][r] = 0.f;

  const int srow = tid >> 3;                       // 0..31
  const int skb  = (tid & 7) ^ (srow & 7);         // swizzled k-block
  const unsigned short* gA = A + (size_t)(brow + srow) * K + skb * 8;
  const unsigned short* gB = BT + (size_t)(bcol + srow) * K + skb * 8;

#define STAGE(b, kt)                                              \
  {                                                               \
    unsigned short* la_ = smem + (b) * 12288 + tid * 8;           \
    unsigned short* lb_ = la_ + 4096;                             \
    gload_lds16(gA + (kt), la_);                                  \
    gload_lds16(gA + (kt) + 32 * K, la_ + 2048);                  \
    gload_lds16(gB + (kt), lb_);                                  \
    gload_lds16(gB + (kt) + 32 * K, lb_ + 2048);                  \
    gload_lds16(gB + (kt) + 64 * K, lb_ + 4096);                  \
    gload_lds16(gB + (kt) + 96 * K, lb_ + 6144);                  \
  }

  STAGE(0, 0);
  asm volatile("s_waitcnt vmcnt(0)" ::: "memory");
  __builtin_amdgcn_s_barrier();

  const int NT = K / 64;
  for (int t = 0; t < NT; ++t) {
    const int cur = t & 1;
    if (t + 1 < NT) STAGE(cur ^ 1, (t + 1) * 64);

    const unsigned short* As = smem + cur * 12288;
    const unsigned short* Bs = As + 4096;
    s16x8 af[4][2], bf[2][2];
#pragma unroll
    for (int m = 0; m < 4; ++m)
#pragma unroll
      for (int ks = 0; ks < 2; ++ks)
        af[m][ks] = *(const s16x8*)(As + (m * 16 + la) * 64 +
                                    (((ks * 4 + hi) ^ (la & 7)) * 8));
#pragma unroll
    for (int n = 0; n < 2; ++n)
#pragma unroll
      for (int ks = 0; ks < 2; ++ks)
        bf[n][ks] = *(const s16x8*)(Bs + (wc + n * 16 + la) * 64 +
                                    (((ks * 4 + hi) ^ (la & 7)) * 8));
#pragma unroll
    for (int m = 0; m < 4; ++m)
#pragma unroll
      for (int n = 0; n < 2; ++n)
#pragma unroll
        for (int ks = 0; ks < 2; ++ks)
          acc[m][n] = __builtin_amdgcn_mfma_f32_16x16x32_bf16(af[m][ks], bf[n][ks],
                                                              acc[m][n], 0, 0, 0);
    asm volatile("s_waitcnt vmcnt(0)" ::: "memory");
    __builtin_amdgcn_sched_barrier(0);
    __builtin_amdgcn_s_barrier();
  }
#undef STAGE

  if constexpr (MODE == 0) {
    // epilogue: C/D layout col=lane&15, row=(lane>>4)*4+reg  [m89-verified]
#pragma unroll
    for (int m = 0; m < 4; ++m) {
      const int row0 = brow + m * 16 + hi * 4;
#pragma unroll
      for (int n = 0; n < 2; ++n) {
        const int col = bcol + wc + n * 16 + la;
        const float bv = bias[col];
#pragma unroll
        for (int r = 0; r < 4; ++r) {
          float v = acc[m][n][r] + bv;
          v = v > 0.f ? v : 0.f;
          outB[(size_t)(row0 + r) * ODIM + col] = f2bf(v);
        }
      }
    }
  } else {
    // ---- fused scatter epilogue ----
    __shared__ int pref[65];
    __shared__ int cbase[64];
    float (*tile)[128] = (float (*)[128])smem;   // 32 KB, reuses staging
    // stage finished tile (+bias+pe) to LDS
#pragma unroll
    for (int m = 0; m < 4; ++m) {
      const int trl = m * 16 + hi * 4;
#pragma unroll
      for (int n = 0; n < 2; ++n) {
        const int lcol = wc + n * 16 + la;
        const int gcol = bcol + lcol;
        const float bv = bias[gcol];
#pragma unroll
        for (int r = 0; r < 4; ++r) {
          const int trow = brow + trl + r;
          int p = trow / NK1; if (p > NPARTS - 1) p = NPARTS - 1;
          tile[trl + r][lcol] = acc[m][n][r] + bv + pe[(size_t)p * ODIM + gcol];
        }
      }
    }
    if (wave == 0) {
      const int trow = brow + lane;              // < 4224 always
      const int c = gcnt[trow];
      int s = c;
#pragma unroll
      for (int off = 1; off < 64; off <<= 1) {
        const int v = __shfl_up(s, off);
        if (lane >= off) s += v;
      }
      pref[lane + 1] = s;
      if (lane == 0) pref[0] = 0;
      int p = trow / NK1; if (p > NPARTS - 1) p = NPARTS - 1;
      cbase[lane] = p * BPART + gbase[trow];
    }
    __syncthreads();
    const int Nit = pref[64];
    const int hw  = wave * 2 + (lane >> 5);      // half-wave id 0..7
    const int l32 = lane & 31;
    for (int iq = hw; iq < Nit; iq += 8) {
      int lo = 0, hh = 64;                       // largest t with pref[t] <= iq
      while (hh - lo > 1) {
        const int mid = (lo + hh) >> 1;
        if (pref[mid] <= iq) lo = mid; else hh = mid;
      }
      const int t = lo;
      const int orow = rowlist[cbase[t] + (iq - pref[t])];
      const f32x4 v = *(const f32x4*)&tile[t][l32 * 4];
      __builtin_nontemporal_store(v, (f32x4*)(outF + (size_t)orow * ODIM + bcol + l32 * 4));
    }
  }
}

// ---------------- launch ----------------
extern "C" void kernel_launch(void* const* d_in, const int* in_sizes, int n_in,
                              void* d_out, int out_size, void* d_ws, size_t ws_size,
                              hipStream_t stream) {
  const int*   hashes = (const int*)d_in[0];
  const float* emb    = (const float*)d_in[1];
  const float* W1     = (const float*)d_in[2];
  const float* b1     = (const float*)d_in[3];
  const float* W2     = (const float*)d_in[4];
  const float* b2     = (const float*)d_in[5];
  const float* pe     = (const float*)d_in[6];
  float* out = (float*)d_out;

  char* ws = (char*)d_ws;
  unsigned short* embB = (unsigned short*)(ws);                 // 4224*768*2  = 6,488,064
  unsigned short* w1t  = (unsigned short*)(ws + 6488064);       // 1024*768*2  = 1,572,864
  unsigned short* w2t  = (unsigned short*)(ws + 8060928);       // 1024*1024*2 = 2,097,152
  unsigned short* H    = (unsigned short*)(ws + 10158080);      // 4224*1024*2 = 8,650,752
  int*            gcnt = (int*)(ws + 18808832);                 // 4224*4
  int*            gbas = (int*)(ws + 18825728);                 // 4224*4
  int*            rowl = (int*)(ws + 18842624);                 // 65536*4 = 262,144
                                                                // total ~19.1 MB

  prep_kernel<<<EMB_BLOCKS + W1_BLOCKS + NPARTS, 256, 0, stream>>>(
      emb, W1, hashes, embB, w1t, gcnt, gbas, rowl);

  // GEMM1 (z=0: 528 gemm blocks) + W2 transpose overlapped (z=1: 256 blocks)
  gemm_kernel<VAE, 0, true><<<dim3(8, 66, 2), 256, 0, stream>>>(
      embB, w1t, b1, nullptr, H, nullptr, W2, w2t, nullptr, nullptr, nullptr);

  // GEMM2 fused with consumer scatter (output write overlaps compute)
  gemm_kernel<ODIM, 2, false><<<dim3(8, 66, 1), 256, 0, stream>>>(
      H, w2t, b2, pe, nullptr, out, nullptr, nullptr, gcnt, gbas, rowl);
}

// Round 5
// 95.364 us; speedup vs baseline: 1.3381x; 1.3381x over previous
//
#include <hip/hip_runtime.h>
#include <stdint.h>

// ---- problem constants ----
#define NPARTS 16
#define NK1    257            // rows per part (hash values 0..256)
#define ROWS   4112           // 257*16 distinct embedding rows
#define MPAD   4224           // 66*64, padded GEMM M
#define VAE    768
#define ODIM   1024
#define BROWS  65536          // 4096*16 output rows

typedef __attribute__((ext_vector_type(4))) float f32x4;
typedef __attribute__((ext_vector_type(8))) short s16x8;

static __device__ __forceinline__ unsigned short f2bf(float f) {
  union { float f; unsigned u; } v; v.f = f;
  unsigned x = v.u;
  unsigned r = x + 0x7FFFu + ((x >> 16) & 1u);   // RNE
  return (unsigned short)(r >> 16);
}

static __device__ __forceinline__ void gload_lds16(const void* g, void* l) {
  __builtin_amdgcn_global_load_lds(
      (const __attribute__((address_space(1))) unsigned int*)g,
      (__attribute__((address_space(3))) unsigned int*)l, 16, 0, 0);
}

// ---------------- prep: cast emb -> bf16 (pad to MPAD rows); transpose-cast W1 ----
#define EMB_BLOCKS 1024
__global__ __launch_bounds__(256) void prep_kernel(
    const float* __restrict__ emb, const float* __restrict__ W1,
    unsigned short* __restrict__ embB, unsigned short* __restrict__ w1t) {
  __shared__ unsigned short tile[32][33];
  const int tid = threadIdx.x;
  const int bid = blockIdx.x;
  if (bid < EMB_BLOCKS) {
    const int NQ = MPAD * VAE / 4;   // 811008 quads
    for (int g = bid * 256 + tid; g < NQ; g += EMB_BLOCKS * 256) {
      const int i4 = g * 4;
      ushort4 o;
      if (i4 < ROWS * VAE) {
        const float4 v = *(const float4*)(emb + i4);
        o.x = f2bf(v.x); o.y = f2bf(v.y); o.z = f2bf(v.z); o.w = f2bf(v.w);
      } else {
        o.x = 0; o.y = 0; o.z = 0; o.w = 0;
      }
      *(ushort4*)(embB + i4) = o;
    }
  } else {
    const int tb = bid - EMB_BLOCKS;         // 768 tiles: 24 k-tiles x 32 n-tiles
    const int nkt = VAE / 32;
    const int tk = (tb % nkt) * 32;
    const int tn = (tb / nkt) * 32;
    const int r  = tid >> 3;                 // k-local
    const int c4 = (tid & 7) * 4;            // n-local
    const float4 v = *(const float4*)(W1 + (size_t)(tk + r) * ODIM + tn + c4);
    tile[r][c4 + 0] = f2bf(v.x);
    tile[r][c4 + 1] = f2bf(v.y);
    tile[r][c4 + 2] = f2bf(v.z);
    tile[r][c4 + 3] = f2bf(v.w);
    __syncthreads();
    ushort4 o;
    o.x = tile[c4 + 0][r];
    o.y = tile[c4 + 1][r];
    o.z = tile[c4 + 2][r];
    o.w = tile[c4 + 3][r];
    *(ushort4*)(w1t + (size_t)(tn + r) * VAE + tk + c4) = o;
  }
}

// ---------------- 64x128-tile bf16 MFMA GEMM ----------------
// 3-buffer LDS pipeline, BK=64, counted vmcnt (never 0 in steady state),
// ONE barrier per K-step, early STAGE issue, setprio around MFMA.
// XOR-swizzled staging: swizzled global src + linear LDS dest [m104/m108],
// swizzled ds_read [rule #21] -> conflict-free ds_read_b128.
// MODE 0: out = relu(acc+bias) -> bf16 H     (+ z==1 blocks transpose-cast W2)
// MODE 2: out = acc+bias+pe[row/257] -> f32 T
template <int K, int MODE, bool DO_W2T>
__global__ __launch_bounds__(256) void gemm_kernel(
    const unsigned short* __restrict__ A, const unsigned short* __restrict__ BT,
    const float* __restrict__ bias, const float* __restrict__ pe,
    unsigned short* __restrict__ outB, float* __restrict__ outF,
    const float* __restrict__ W2src, unsigned short* __restrict__ w2dst) {
  __shared__ __align__(16) unsigned short smem[3 * 12288];   // 72 KB: 3 x (A 8K + B 16K)B
  const int tid = threadIdx.x;

  if (DO_W2T && blockIdx.z == 1) {
    if (blockIdx.y >= 32) return;
    unsigned short (*ttile)[132] = (unsigned short (*)[132])smem;
    const int tk = blockIdx.y * 32, tn = blockIdx.x * 128;
#pragma unroll
    for (int q = 0; q < 4; ++q) {
      const int row = (tid >> 5) + q * 8, c4 = (tid & 31) * 4;
      const float4 v = *(const float4*)(W2src + (size_t)(tk + row) * ODIM + tn + c4);
      ttile[row][c4 + 0] = f2bf(v.x); ttile[row][c4 + 1] = f2bf(v.y);
      ttile[row][c4 + 2] = f2bf(v.z); ttile[row][c4 + 3] = f2bf(v.w);
    }
    __syncthreads();
#pragma unroll
    for (int q = 0; q < 4; ++q) {
      const int n = (tid >> 3) + q * 32, k4 = (tid & 7) * 4;
      ushort4 o;
      o.x = ttile[k4 + 0][n]; o.y = ttile[k4 + 1][n];
      o.z = ttile[k4 + 2][n]; o.w = ttile[k4 + 3][n];
      *(ushort4*)(w2dst + (size_t)(tn + n) * ODIM + tk + k4) = o;
    }
    return;
  }

  const int lane = tid & 63;
  const int wave = tid >> 6;
  const int wc   = wave * 32;
  const int brow = blockIdx.y * 64;
  const int bcol = blockIdx.x * 128;
  const int la   = lane & 15;
  const int hi   = lane >> 4;

  f32x4 acc[4][2];
#pragma unroll
  for (int m = 0; m < 4; ++m)
#pragma unroll
    for (int n = 0; n < 2; ++n)
#pragma unroll
      for (int r = 0; r < 4; ++r) acc[m][n][r] = 0.f;

  const int srow = tid >> 3;                       // 0..31
  const int skb  = (tid & 7) ^ (srow & 7);         // swizzled k-block
  const unsigned short* gA = A + (size_t)(brow + srow) * K + skb * 8;
  const unsigned short* gB = BT + (size_t)(bcol + srow) * K + skb * 8;

  // 6 gload_lds per thread per stage (A: 2x4KB chunks, B: 4x4KB chunks)
#define STAGE(b, kt)                                              \
  {                                                               \
    unsigned short* la_ = smem + (b) * 12288 + tid * 8;           \
    unsigned short* lb_ = la_ + 4096;                             \
    gload_lds16(gA + (kt), la_);                                  \
    gload_lds16(gA + (kt) + 32 * K, la_ + 2048);                  \
    gload_lds16(gB + (kt), lb_);                                  \
    gload_lds16(gB + (kt) + 32 * K, lb_ + 2048);                  \
    gload_lds16(gB + (kt) + 64 * K, lb_ + 4096);                  \
    gload_lds16(gB + (kt) + 96 * K, lb_ + 6144);                  \
  }

  const int NT = K / 64;     // 12 or 16
  STAGE(0, 0);
  STAGE(1, 64);

#pragma unroll
  for (int t = 0; t < NT; ++t) {
    // stage-t loads retired (6 = stage t+1 stays in flight); last iter drains
    if (t < NT - 1) asm volatile("s_waitcnt vmcnt(6)" ::: "memory");
    else            asm volatile("s_waitcnt vmcnt(0)" ::: "memory");
    __builtin_amdgcn_sched_barrier(0);
    __builtin_amdgcn_s_barrier();
    // early prefetch issue: overwrites buf (t-1)%3, whose reads all waves
    // retired before their iter-(t-1) lgkmcnt(0) -> before this barrier
    if (t + 2 < NT) STAGE((t + 2) % 3, (t + 2) * 64);

    const unsigned short* As = smem + (t % 3) * 12288;
    const unsigned short* Bs = As + 4096;
    s16x8 af[4][2], bf[2][2];
#pragma unroll
    for (int m = 0; m < 4; ++m)
#pragma unroll
      for (int ks = 0; ks < 2; ++ks)
        af[m][ks] = *(const s16x8*)(As + (m * 16 + la) * 64 +
                                    (((ks * 4 + hi) ^ (la & 7)) * 8));
#pragma unroll
    for (int n = 0; n < 2; ++n)
#pragma unroll
      for (int ks = 0; ks < 2; ++ks)
        bf[n][ks] = *(const s16x8*)(Bs + (wc + n * 16 + la) * 64 +
                                    (((ks * 4 + hi) ^ (la & 7)) * 8));
    // pin read-retirement before next iteration's barrier (rule #18)
    asm volatile("s_waitcnt lgkmcnt(0)" ::: "memory");
    __builtin_amdgcn_sched_barrier(0);

    __builtin_amdgcn_s_setprio(1);
#pragma unroll
    for (int m = 0; m < 4; ++m)
#pragma unroll
      for (int n = 0; n < 2; ++n)
#pragma unroll
        for (int ks = 0; ks < 2; ++ks)
          acc[m][n] = __builtin_amdgcn_mfma_f32_16x16x32_bf16(af[m][ks], bf[n][ks],
                                                              acc[m][n], 0, 0, 0);
    __builtin_amdgcn_s_setprio(0);
  }
#undef STAGE

  // epilogue: C/D layout col=lane&15, row=(lane>>4)*4+reg  [m89-verified]
#pragma unroll
  for (int m = 0; m < 4; ++m) {
    const int row0 = brow + m * 16 + hi * 4;
#pragma unroll
    for (int n = 0; n < 2; ++n) {
      const int col = bcol + wc + n * 16 + la;
      const float bv = bias[col];
      if (MODE == 0) {
#pragma unroll
        for (int r = 0; r < 4; ++r) {
          float v = acc[m][n][r] + bv;
          v = v > 0.f ? v : 0.f;
          outB[(size_t)(row0 + r) * ODIM + col] = f2bf(v);
        }
      } else {
#pragma unroll
        for (int r = 0; r < 4; ++r) {
          const int row = row0 + r;
          int p = row / NK1;
          if (p > NPARTS - 1) p = NPARTS - 1;   // padded rows: never gathered
          outF[(size_t)row * ODIM + col] = acc[m][n][r] + bv + pe[(size_t)p * ODIM + col];
        }
      }
    }
  }
}

// ---------------- gather: out[row] = T[hash + (row&15)*257]  (bias+pe folded into T) ----
__global__ __launch_bounds__(256) void gather_kernel(const int* __restrict__ hashes,
                                                     const float* __restrict__ T,
                                                     float* __restrict__ out) {
  const int wid  = (blockIdx.x * blockDim.x + threadIdx.x) >> 6;
  const int lane = threadIdx.x & 63;
  const int nw   = (gridDim.x * blockDim.x) >> 6;
  for (int row = wid; row < BROWS; row += nw) {
    const int h = __builtin_amdgcn_readfirstlane(hashes[row]);
    const int p = row & (NPARTS - 1);
    const f32x4* __restrict__ src = (const f32x4*)(T + (size_t)(h + p * NK1) * ODIM);
    f32x4* __restrict__ dst = (f32x4*)(out + (size_t)row * ODIM);
#pragma unroll
    for (int j = 0; j < 4; ++j) {
      f32x4 v = src[lane + j * 64];
      __builtin_nontemporal_store(v, dst + lane + j * 64);
    }
  }
}

// ---------------- launch ----------------
extern "C" void kernel_launch(void* const* d_in, const int* in_sizes, int n_in,
                              void* d_out, int out_size, void* d_ws, size_t ws_size,
                              hipStream_t stream) {
  const int*   hashes = (const int*)d_in[0];
  const float* emb    = (const float*)d_in[1];
  const float* W1     = (const float*)d_in[2];
  const float* b1     = (const float*)d_in[3];
  const float* W2     = (const float*)d_in[4];
  const float* b2     = (const float*)d_in[5];
  const float* pe     = (const float*)d_in[6];
  float* out = (float*)d_out;

  char* ws = (char*)d_ws;
  unsigned short* embB = (unsigned short*)(ws);                 // 4224*768*2  = 6,488,064
  unsigned short* w1t  = (unsigned short*)(ws + 6488064);       // 1024*768*2  = 1,572,864
  unsigned short* w2t  = (unsigned short*)(ws + 8060928);       // 1024*1024*2 = 2,097,152
  unsigned short* H    = (unsigned short*)(ws + 10158080);      // 4224*1024*2 = 8,650,752
  float*          T    = (float*)(ws + 18808832);               // 4224*1024*4 = 17,301,504

  prep_kernel<<<EMB_BLOCKS + 768, 256, 0, stream>>>(emb, W1, embB, w1t);

  // GEMM1 (z=0: 528 gemm blocks) + W2 transpose overlapped (z=1: 256 blocks)
  gemm_kernel<VAE, 0, true><<<dim3(8, 66, 2), 256, 0, stream>>>(
      embB, w1t, b1, nullptr, H, nullptr, W2, w2t);

  gemm_kernel<ODIM, 2, false><<<dim3(8, 66, 1), 256, 0, stream>>>(
      H, w2t, b2, pe, nullptr, T, nullptr, nullptr);

  gather_kernel<<<2048, 256, 0, stream>>>(hashes, T, out);
}